// Round 3
// baseline (374.919 us; speedup 1.0000x reference)
//
#include <hip/hip_runtime.h>

// Problem constants
#define BB 256          // batch
#define FF 128          // features
#define CC 100          // classes
#define KG 512          // split-K groups (blocks of main_gemm)
#define ITPB 16         // it-pairs per main_gemm block (KG*ITPB = 8192)

typedef short bf16x8 __attribute__((ext_vector_type(8)));
typedef float f32x4 __attribute__((ext_vector_type(4)));
typedef _Float16 f16x8 __attribute__((ext_vector_type(8)));

// Raw barrier: waits LDS ops only, leaves global loads (vmcnt) in flight.
// __syncthreads() would emit s_waitcnt vmcnt(0) and drain the prefetch.
#define LDS_BARRIER() asm volatile("s_waitcnt lgkmcnt(0)\n\ts_barrier" ::: "memory")

static __device__ inline unsigned short f2bf(float f) {
    unsigned u = __float_as_uint(f);
    u += 0x7fffu + ((u >> 16) & 1u);   // RNE
    return (unsigned short)(u >> 16);
}
static __device__ inline float bf2f(unsigned short h) {
    return __uint_as_float(((unsigned)h) << 16);
}

// ---------------------------------------------------------------------------
// Kernel 1: fv[row][b] = sigmoid(x[b,:] . sel_W[row,:] + sel_b[row])  (bf16)
// row = it*6 + d, so fv[row*256+b] == fv[it][d][b].
// ---------------------------------------------------------------------------
__global__ __launch_bounds__(256) void fv_kernel(
    const float* __restrict__ x, const float* __restrict__ selW,
    const float* __restrict__ selb, unsigned short* __restrict__ fvout)
{
    __shared__ unsigned short wt[128 * 136];
    __shared__ unsigned short xt[128 * 136];
    __shared__ float sb[128];

    const int tid = threadIdx.x;
    const int m0 = blockIdx.x * 128;  // sel row base
    const int n0 = blockIdx.y * 128;  // b base

    #pragma unroll 4
    for (int pass = 0; pass < 16; ++pass) {
        int idx = pass * 256 + tid;
        int r = idx >> 5, f4 = idx & 31;
        float4 v = *((const float4*)(selW + (size_t)(m0 + r) * FF) + f4);
        float4 vx = *((const float4*)(x + (size_t)(n0 + r) * FF) + f4);
        ushort4 h;
        h.x = f2bf(v.x); h.y = f2bf(v.y); h.z = f2bf(v.z); h.w = f2bf(v.w);
        *(ushort4*)(wt + r * 136 + f4 * 4) = h;
        ushort4 hx;
        hx.x = f2bf(vx.x); hx.y = f2bf(vx.y); hx.z = f2bf(vx.z); hx.w = f2bf(vx.w);
        *(ushort4*)(xt + r * 136 + f4 * 4) = hx;
    }
    if (tid < 128) sb[tid] = selb[m0 + tid];
    __syncthreads();

    const int w = tid >> 6, lane = tid & 63;
    const int q = lane >> 4, l15 = lane & 15;
    const int mq = w & 1, nq = w >> 1;

    f32x4 zero4 = {0.f, 0.f, 0.f, 0.f};
    f32x4 acc[4][4];
    #pragma unroll
    for (int i = 0; i < 4; ++i)
        #pragma unroll
        for (int j = 0; j < 4; ++j) acc[i][j] = zero4;

    #pragma unroll
    for (int ch = 0; ch < 4; ++ch) {
        bf16x8 a[4];
        #pragma unroll
        for (int ms = 0; ms < 4; ++ms)
            a[ms] = *(const bf16x8*)(wt + (mq * 64 + ms * 16 + l15) * 136 + ch * 32 + q * 8);
        #pragma unroll
        for (int ns = 0; ns < 4; ++ns) {
            bf16x8 bfr = *(const bf16x8*)(xt + (nq * 64 + ns * 16 + l15) * 136 + ch * 32 + q * 8);
            #pragma unroll
            for (int ms = 0; ms < 4; ++ms)
                acc[ms][ns] = __builtin_amdgcn_mfma_f32_16x16x32_bf16(a[ms], bfr, acc[ms][ns], 0, 0, 0);
        }
    }

    #pragma unroll
    for (int ms = 0; ms < 4; ++ms) {
        int rowl = mq * 64 + ms * 16 + q * 4;
        #pragma unroll
        for (int ns = 0; ns < 4; ++ns) {
            int b = n0 + nq * 64 + ns * 16 + l15;
            #pragma unroll
            for (int reg = 0; reg < 4; ++reg) {
                int row = m0 + rowl + reg;
                float z = acc[ms][ns][reg] + sb[rowl + reg];
                float p = 1.0f / (1.0f + __expf(-z));
                fvout[(size_t)row * 256 + b] = f2bf(p);
            }
        }
    }
}

// ---------------------------------------------------------------------------
// Kernel 2: split-K GEMM, prefetch distance 2 (register double-buffer).
// block = 256 thr (4 waves), out tile = 256 b x 112 c, 16 it-pairs per block.
// Partials fp16: part16[b][kg][c], c padded to 112.
// ---------------------------------------------------------------------------
__global__ __launch_bounds__(256, 2) void main_gemm(
    const unsigned short* __restrict__ fv, const float* __restrict__ outW,
    _Float16* __restrict__ part16)
{
    __shared__ unsigned short leaf[256 * 72]; // stride 72 bf16: %32dw==4 -> conflict-free
    __shared__ unsigned short wt[112 * 72];

    const int tid = threadIdx.x;
    const int kg = blockIdx.x;
    const int w = tid >> 6, lane = tid & 63;
    const int q = lane >> 4, l15 = lane & 15;
    const int cc = tid >> 4, f4 = tid & 15;

    f32x4 zero4 = {0.f, 0.f, 0.f, 0.f};
    f32x4 acc[4][7];
    #pragma unroll
    for (int i = 0; i < 4; ++i)
        #pragma unroll
        for (int j = 0; j < 7; ++j) acc[i][j] = zero4;

    // -------- prologue: prefetch tiles 0 and 1 into two register buffers ----
    float4 wv[2][7];
    unsigned short pv[2][6];
    #pragma unroll
    for (int pb = 0; pb < 2; ++pb) {
        const int it = kg * ITPB + pb;
        #pragma unroll
        for (int pass = 0; pass < 7; ++pass) {
            const int c = pass * 16 + cc;
            float4 v = make_float4(0.f, 0.f, 0.f, 0.f);
            if (c < CC)
                v = *((const float4*)(outW + (size_t)c * 524288 + (size_t)it * 64) + f4);
            wv[pb][pass] = v;   // c>=100 lanes stay zero forever (never reloaded)
        }
        const unsigned short* fp = fv + (size_t)it * 1536 + tid;
        #pragma unroll
        for (int d = 0; d < 6; ++d) pv[pb][d] = fp[d * 256];
    }

    #pragma unroll 2
    for (int itl = 0; itl < ITPB; ++itl) {
        const int cur = itl & 1;
        LDS_BARRIER();   // prev iteration's MFMA LDS reads complete (lgkm only)

        // (1) consume wv[cur]: convert fp32 -> bf16, stage wt tile
        #pragma unroll
        for (int pass = 0; pass < 7; ++pass) {
            const int c = pass * 16 + cc;
            ushort4 h;
            h.x = f2bf(wv[cur][pass].x); h.y = f2bf(wv[cur][pass].y);
            h.z = f2bf(wv[cur][pass].z); h.w = f2bf(wv[cur][pass].w);
            *(ushort4*)(wt + c * 72 + f4 * 4) = h;
        }

        // (2) consume pv[cur]: leaf generation for b = tid (tree-factorized)
        {
            float p0 = bf2f(pv[cur][0]), p1 = bf2f(pv[cur][1]), p2 = bf2f(pv[cur][2]);
            float p3 = bf2f(pv[cur][3]), p4 = bf2f(pv[cur][4]), p5 = bf2f(pv[cur][5]);
            float q0 = 1.f - p0, q1 = 1.f - p1, q2 = 1.f - p2;
            float q3 = 1.f - p3, q4 = 1.f - p4, q5 = 1.f - p5;
            float A[4]  = {p0 * p1, p0 * q1, q0 * p1, q0 * q1};
            float B2[4] = {p2 * p3, p2 * q3, q2 * p3, q2 * q3};
            float C2[4] = {p4 * p5, p4 * q5, q4 * p5, q4 * q5};
            float BC[16];
            #pragma unroll
            for (int m = 0; m < 16; ++m) BC[m] = B2[m >> 2] * C2[m & 3];
            unsigned short* row = leaf + tid * 72;
            #pragma unroll
            for (int j = 0; j < 8; ++j) {
                uint4 dw;
                unsigned int* dwp = (unsigned int*)&dw;
                #pragma unroll
                for (int e = 0; e < 4; ++e) {
                    int l0 = j * 8 + 2 * e;
                    float v0 = A[l0 >> 4] * BC[l0 & 15];
                    float v1 = A[(l0 + 1) >> 4] * BC[(l0 + 1) & 15];
                    dwp[e] = (unsigned)f2bf(v0) | ((unsigned)f2bf(v1) << 16);
                }
                *(uint4*)(row + j * 8) = dw;
            }
        }

        // (3) reissue prefetch for tile itl+2 into buffer `cur` (wraps; harmless)
        {
            const int itn = kg * ITPB + ((itl + 2) & (ITPB - 1));
            #pragma unroll
            for (int pass = 0; pass < 7; ++pass) {
                const int c = pass * 16 + cc;
                if (c < CC)
                    wv[cur][pass] = *((const float4*)(outW + (size_t)c * 524288 + (size_t)itn * 64) + f4);
            }
            const unsigned short* fp = fv + (size_t)itn * 1536 + tid;
            #pragma unroll
            for (int d = 0; d < 6; ++d) pv[cur][d] = fp[d * 256];
        }

        LDS_BARRIER();   // LDS writes visible; prefetch loads stay in flight

        // (4) MFMA over LDS
        #pragma unroll
        for (int ch = 0; ch < 2; ++ch) {
            bf16x8 a[4];
            #pragma unroll
            for (int ms = 0; ms < 4; ++ms)
                a[ms] = *(const bf16x8*)(leaf + (w * 64 + ms * 16 + l15) * 72 + ch * 32 + q * 8);
            #pragma unroll
            for (int nt = 0; nt < 7; ++nt) {
                bf16x8 bb = *(const bf16x8*)(wt + (nt * 16 + l15) * 72 + ch * 32 + q * 8);
                #pragma unroll
                for (int ms = 0; ms < 4; ++ms)
                    acc[ms][nt] = __builtin_amdgcn_mfma_f32_16x16x32_bf16(a[ms], bb, acc[ms][nt], 0, 0, 0);
            }
        }
    }

    // epilogue: fp16 partials part16[b][kg][c]
    #pragma unroll
    for (int ms = 0; ms < 4; ++ms) {
        const int brow = w * 64 + ms * 16 + q * 4;
        #pragma unroll
        for (int nt = 0; nt < 7; ++nt) {
            const int c = nt * 16 + l15;
            #pragma unroll
            for (int reg = 0; reg < 4; ++reg)
                part16[((size_t)(brow + reg) * KG + kg) * 112 + c] =
                    (_Float16)acc[ms][nt][reg];
        }
    }
}

// ---------------------------------------------------------------------------
// Kernel 3: out[b][c] = sum_kg part16[b][kg][c] + out_b[c]
// One block per b; slice = 512*112 halves = 114688 B contiguous.
// 224 active threads; thread t owns c-octet t%14, kg subgroup t/14 (16 groups).
// uint4 index i*224+t is fully contiguous across the block.
// ---------------------------------------------------------------------------
__global__ __launch_bounds__(256) void reduce_k(
    const _Float16* __restrict__ part16, const float* __restrict__ outb,
    float* __restrict__ out)
{
    __shared__ float red[16 * 112];
    const int b = blockIdx.x;
    const int tid = threadIdx.x;
    const f16x8* slice = (const f16x8*)(part16 + (size_t)b * (KG * 112));

    if (tid < 224) {
        const int c8 = tid % 14;       // c base = c8*8
        const int kgs = tid / 14;      // 0..15
        float s[8];
        #pragma unroll
        for (int j = 0; j < 8; ++j) s[j] = 0.f;
        #pragma unroll 4
        for (int i = 0; i < 32; ++i) { // kg = i*16 + kgs
            f16x8 v = slice[i * 224 + tid];
            #pragma unroll
            for (int j = 0; j < 8; ++j) s[j] += (float)v[j];
        }
        #pragma unroll
        for (int j = 0; j < 8; ++j) red[kgs * 112 + c8 * 8 + j] = s[j];
    }
    __syncthreads();
    if (tid < CC) {
        float r = outb[tid];
        #pragma unroll
        for (int k = 0; k < 16; ++k) r += red[k * 112 + tid];
        out[b * CC + tid] = r;
    }
}

extern "C" void kernel_launch(void* const* d_in, const int* in_sizes, int n_in,
                              void* d_out, int out_size, void* d_ws, size_t ws_size,
                              hipStream_t stream) {
    const float* x    = (const float*)d_in[0];
    const float* selW = (const float*)d_in[1];
    const float* selb = (const float*)d_in[2];
    const float* outW = (const float*)d_in[3];
    const float* outb = (const float*)d_in[4];
    float* out = (float*)d_out;

    // ws: fv bf16 [49152*256] = 25,165,824 B ; part16 [256][512][112] = 29,360,128 B
    unsigned short* fv = (unsigned short*)d_ws;
    _Float16* part16 = (_Float16*)((char*)d_ws + 25165824);

    fv_kernel<<<dim3(384, 2), 256, 0, stream>>>(x, selW, selb, fv);
    main_gemm<<<KG, 256, 0, stream>>>(fv, outW, part16);
    reduce_k<<<BB, 256, 0, stream>>>(part16, outb, out);
}